// Round 14
// baseline (157.035 us; speedup 1.0000x reference)
//
#include <hip/hip_runtime.h>
#include <hip/hip_fp16.h>
#include <math.h>
#include <stdint.h>

#define NRAYS   1048576
#define NSPH    4
#define TEXH    2048
#define TEXW    2048
#define DIN     16
#define HID     32
#define NOUT    3
#define LN_EPS  1e-5f

#define CX      325.79013f           // 2047/(2*pi)
#define CY      651.58025f           // 2047/pi

// Quad-packed u8 table (validated R12/R13): Q[s][y][x] = 2x2 texel block, 16B.
#define QROWS   2048
#define QW      1024
#define Q_BYTES ((size_t)NSPH * QROWS * QW * 16)   // 128 MiB

// prepped MFMA params in ws after Q
#define WF_OFF   Q_BYTES                   // 7 A-frags  x 64 lanes x 16B
#define BI_OFF   (WF_OFF + 7*64*16)        // 4 layers   x 64 lanes x 2 floatx4
#define LP_OFF   (BI_OFF + (size_t)4*64*32)// 3 LN trans x 64 lanes x 4 floatx4
#define WS_NEEDED (LP_OFF + (size_t)3*64*64)

#define SB() __builtin_amdgcn_sched_barrier(0)

typedef _Float16 half8  __attribute__((ext_vector_type(8)));
typedef float    floatx4 __attribute__((ext_vector_type(4)));

__device__ __forceinline__ int pkh(float a, float b) {
    return __builtin_bit_cast(int, __builtin_amdgcn_cvt_pkrtz(a, b));
}

// ---------------- pass 1: relayout fp32 -> u8 quad (validated) ----------------
__device__ __forceinline__ uint32_t pack8(const float4 v) {
    const uint32_t r = (uint32_t)(v.x * 255.0f + 0.5f);
    const uint32_t g = (uint32_t)(v.y * 255.0f + 0.5f);
    const uint32_t b = (uint32_t)(v.z * 255.0f + 0.5f);
    const uint32_t a = (uint32_t)(v.w * 255.0f + 0.5f);
    return r | (g << 8) | (b << 16) | (a << 24);
}

__global__ __launch_bounds__(256) void relayout_kernel(
    const float* __restrict__ tex, uint4* __restrict__ Q)
{
    const int x = blockIdx.x * 256 + threadIdx.x;
    const int y = blockIdx.y;
    const int s = blockIdx.z;
    const int y1 = min(y + 1, TEXH - 1);
    const float4* img = reinterpret_cast<const float4*>(tex) + (size_t)s * TEXH * TEXW;
    const float4 t00 = img[(size_t)y  * TEXW + x];
    const float4 t01 = img[(size_t)y  * TEXW + x + 1];
    const float4 t10 = img[(size_t)y1 * TEXW + x];
    const float4 t11 = img[(size_t)y1 * TEXW + x + 1];
    uint4 q;
    q.x = pack8(t00); q.y = pack8(t01); q.z = pack8(t10); q.w = pack8(t11);
    Q[((size_t)s * QROWS + y) * QW + x] = q;
}

// ---------------- pass 1b: bake W^T A-frags, biases, LN params (validated) ----------------
__global__ __launch_bounds__(64) void prep_w(
    const float* __restrict__ w_in,  const float* __restrict__ b_in,
    const float* __restrict__ g_in,  const float* __restrict__ bt_in,
    const float* __restrict__ w_hid, const float* __restrict__ b_hid,
    const float* __restrict__ g_hid, const float* __restrict__ bt_hid,
    const float* __restrict__ w_out, const float* __restrict__ b_out,
    char* __restrict__ wsb)
{
    const int l  = threadIdx.x;          // 0..63
    const int m  = l & 15;
    const int kg = l >> 4;
    int4* WF = (int4*)(wsb + WF_OFF);

    #pragma unroll
    for (int f = 0; f < 2; ++f) {
        half8 v;
        #pragma unroll
        for (int j = 0; j < 8; ++j) {
            const int k = kg * 8 + j;
            v[j] = (_Float16)((k < DIN) ? w_in[k * HID + f * 16 + m] : 0.0f);
        }
        WF[f * 64 + l] = __builtin_bit_cast(int4, v);
    }
    #pragma unroll
    for (int t = 0; t < 2; ++t)
        #pragma unroll
        for (int hf = 0; hf < 2; ++hf) {
            half8 v;
            #pragma unroll
            for (int j = 0; j < 8; ++j) {
                const int k = kg * 8 + j;
                v[j] = (_Float16)w_hid[t * HID * HID + k * HID + hf * 16 + m];
            }
            WF[(2 + t * 2 + hf) * 64 + l] = __builtin_bit_cast(int4, v);
        }
    {
        half8 v;
        #pragma unroll
        for (int j = 0; j < 8; ++j) {
            const int k = kg * 8 + j;
            v[j] = (_Float16)((m < NOUT) ? w_out[k * NOUT + m] : 0.0f);
        }
        WF[6 * 64 + l] = __builtin_bit_cast(int4, v);
    }

    floatx4* BI = (floatx4*)(wsb + BI_OFF);
    const int r0 = kg * 4;
    floatx4 lo, hi;
    #pragma unroll
    for (int i = 0; i < 4; ++i) { lo[i] = b_in[r0 + i]; hi[i] = b_in[16 + r0 + i]; }
    BI[(0 * 64 + l) * 2 + 0] = lo; BI[(0 * 64 + l) * 2 + 1] = hi;
    #pragma unroll
    for (int i = 0; i < 4; ++i) { lo[i] = b_hid[r0 + i]; hi[i] = b_hid[16 + r0 + i]; }
    BI[(1 * 64 + l) * 2 + 0] = lo; BI[(1 * 64 + l) * 2 + 1] = hi;
    #pragma unroll
    for (int i = 0; i < 4; ++i) { lo[i] = b_hid[32 + r0 + i]; hi[i] = b_hid[48 + r0 + i]; }
    BI[(2 * 64 + l) * 2 + 0] = lo; BI[(2 * 64 + l) * 2 + 1] = hi;
    #pragma unroll
    for (int i = 0; i < 4; ++i) { lo[i] = (r0 + i < NOUT) ? b_out[r0 + i] : 0.0f; hi[i] = 0.0f; }
    BI[(3 * 64 + l) * 2 + 0] = lo; BI[(3 * 64 + l) * 2 + 1] = hi;

    floatx4* LP = (floatx4*)(wsb + LP_OFF);
    floatx4 a, b, c, d;
    #pragma unroll
    for (int i = 0; i < 4; ++i) {
        a[i] = g_in[r0 + i];  b[i] = g_in[16 + r0 + i];
        c[i] = bt_in[r0 + i]; d[i] = bt_in[16 + r0 + i];
    }
    LP[(0 * 64 + l) * 4 + 0] = a; LP[(0 * 64 + l) * 4 + 1] = b;
    LP[(0 * 64 + l) * 4 + 2] = c; LP[(0 * 64 + l) * 4 + 3] = d;
    #pragma unroll
    for (int t = 0; t < 2; ++t) {
        #pragma unroll
        for (int i = 0; i < 4; ++i) {
            a[i] = g_hid[t * 32 + r0 + i];  b[i] = g_hid[t * 32 + 16 + r0 + i];
            c[i] = bt_hid[t * 32 + r0 + i]; d[i] = bt_hid[t * 32 + 16 + r0 + i];
        }
        LP[((1 + t) * 64 + l) * 4 + 0] = a; LP[((1 + t) * 64 + l) * 4 + 1] = b;
        LP[((1 + t) * 64 + l) * 4 + 2] = c; LP[((1 + t) * 64 + l) * 4 + 3] = d;
    }
}

// ---------------- LN + re-fragment (validated R13) ----------------
__device__ __forceinline__ half8 ln_b(int t, floatx4 a0, floatx4 a1,
                                      int lane, const floatx4* __restrict__ LP) {
    float s = 0.0f, q = 0.0f;
    #pragma unroll
    for (int i = 0; i < 4; ++i) {
        s += a0[i] + a1[i];
        q = fmaf(a0[i], a0[i], q);
        q = fmaf(a1[i], a1[i], q);
    }
    s += __shfl_xor(s, 16);
    s += __shfl_xor(s, 32);
    q += __shfl_xor(q, 16);
    q += __shfl_xor(q, 32);
    const float m   = s * (1.0f / 32.0f);
    const float var = fmaf(q, 1.0f / 32.0f, -m * m);
    const float r   = rsqrtf(var + LN_EPS);
    const floatx4 g0 = LP[(t * 64 + lane) * 4 + 0];
    const floatx4 g1 = LP[(t * 64 + lane) * 4 + 1];
    const floatx4 b0 = LP[(t * 64 + lane) * 4 + 2];
    const floatx4 b1 = LP[(t * 64 + lane) * 4 + 3];
    float h0[4], h1[4];
    #pragma unroll
    for (int i = 0; i < 4; ++i) {
        h0[i] = fmaxf(0.0f, fmaf((a0[i] - m) * r, g0[i], b0[i]));
        h1[i] = fmaxf(0.0f, fmaf((a1[i] - m) * r, g1[i], b1[i]));
    }
    const int ph0 = pkh(h0[0], h0[1]), ph1 = pkh(h0[2], h0[3]);
    const int ph2 = pkh(h1[0], h1[1]), ph3 = pkh(h1[2], h1[3]);
    const int c = lane & 15, G = lane >> 4;
    const int slo = ((G & 1) * 32 + c) * 4;
    int bdw[4];
    #pragma unroll
    for (int d = 0; d < 4; ++d) {
        const int sl  = slo + (d >> 1) * 64;
        const int plo = (d & 1) ? ph1 : ph0;
        const int phi = (d & 1) ? ph3 : ph2;
        const int rlo = __builtin_amdgcn_ds_bpermute(sl, plo);
        const int rhi = __builtin_amdgcn_ds_bpermute(sl, phi);
        bdw[d] = (G < 2) ? rlo : rhi;
    }
    const int4 bi = make_int4(bdw[0], bdw[1], bdw[2], bdw[3]);
    return __builtin_bit_cast(half8, bi);
}

// ---------------- gather helper: 2 spheres of one ray -> 4 packed f16 dwords ----------------
__device__ __forceinline__ float ubv(uint32_t w, int c) {
    return (float)((w >> (8 * c)) & 0xFFu);
}

// ---------------- pass 2: lane-specialized gather + MFMA MLP ----------------
__global__ __launch_bounds__(256, 3) void ray_mlp_mfma(
    const float* __restrict__ inputs,
    const uint4* __restrict__ Q,
    const char* __restrict__ wsb,
    float* __restrict__ out)
{
    const int lane = threadIdx.x & 63;
    const int wv   = threadIdx.x >> 6;
    const int ray_base = blockIdx.x * 256 + wv * 64;

    const int c = lane & 15;          // ray column
    const int u = (lane >> 4) & 1;    // feature half (spheres 2u, 2u+1)
    const int p = lane >> 5;          // ray pair: rays p*32+c, p*32+16+c

    const int rA = ray_base + p * 32 + c;
    const int rB = rA + 16;

    // angles for this lane's two spheres of its two rays (one float4 each)
    const float4 angA = *reinterpret_cast<const float4*>(inputs + (size_t)rA * 8 + 4 * u);
    const float4 angB = *reinterpret_cast<const float4*>(inputs + (size_t)rB * 8 + 4 * u);

    const int s0 = 2 * u;

    // ---- addresses for 4 quad loads ----
    float xf[4], yf[4], fm[4];
    uint32_t off[4];
    const float thv[4] = {angA.x, angA.z, angB.x, angB.z};
    const float phv[4] = {angA.y, angA.w, angB.y, angB.w};
    #pragma unroll
    for (int i = 0; i < 4; ++i) {
        const int s = s0 + (i & 1);
        float fx = thv[i] * CX;
        float fy = phv[i] * CY;
        const bool fin = isfinite(fx) && isfinite(fy);
        fm[i] = fin ? (1.0f / 255.0f) : 0.0f;
        fx = fin ? fx : 0.0f;
        fy = fin ? fy : 0.0f;
        const float fx0 = floorf(fx), fy0 = floorf(fy);
        xf[i] = fx - fx0;
        yf[i] = fy - fy0;
        const uint32_t x0 = (uint32_t)min(max((int)fx0, 0), QW - 1);
        const uint32_t y0 = (uint32_t)min(max((int)fy0, 0), QROWS - 1);
        off[i] = ((((uint32_t)s << 11) + y0) << 10) + x0;
    }

    // issue all 4 quad loads + A-frag loads
    uint4 q0 = Q[off[0]];
    uint4 q1 = Q[off[1]];
    uint4 q2 = Q[off[2]];
    uint4 q3 = Q[off[3]];
    const int4* WF = (const int4*)(wsb + WF_OFF);
    int4 af0 = WF[0 * 64 + lane], af1 = WF[1 * 64 + lane];
    int4 af2 = WF[2 * 64 + lane], af3 = WF[3 * 64 + lane];
    int4 af4 = WF[4 * 64 + lane], af5 = WF[5 * 64 + lane];
    int4 af6 = WF[6 * 64 + lane];
    SB();

    // ---- bilinear -> 8 features per ray, packed to 4 dwords each ----
    float fA[8], fB[8];
    {
        const uint4 qq[4] = {q0, q1, q2, q3};
        #pragma unroll
        for (int i = 0; i < 4; ++i) {
            const float xfs = xf[i], yfs = yf[i], m = fm[i];
            float* dst = (i < 2) ? fA : fB;
            const int base = (i & 1) * 4;
            #pragma unroll
            for (int ch = 0; ch < 4; ++ch) {
                const float f00 = ubv(qq[i].x, ch);
                const float f01 = ubv(qq[i].y, ch);
                const float f10 = ubv(qq[i].z, ch);
                const float f11 = ubv(qq[i].w, ch);
                const float top = fmaf(xfs, f01 - f00, f00);
                const float bot = fmaf(xfs, f11 - f10, f10);
                dst[base + ch] = fmaf(yfs, bot - top, top) * m;
            }
        }
    }
    const int dA0 = pkh(fA[0], fA[1]), dA1 = pkh(fA[2], fA[3]);
    const int dA2 = pkh(fA[4], fA[5]), dA3 = pkh(fA[6], fA[7]);
    const int dB0 = pkh(fB[0], fB[1]), dB1 = pkh(fB[2], fB[3]);
    const int dB2 = pkh(fB[4], fB[5]), dB3 = pkh(fB[6], fB[7]);

    const floatx4* BI = (const floatx4*)(wsb + BI_OFF);
    const floatx4* LP = (const floatx4*)(wsb + LP_OFF);

    const floatx4 bi00 = BI[(0 * 64 + lane) * 2 + 0];
    const floatx4 bi01 = BI[(0 * 64 + lane) * 2 + 1];
    const floatx4 bi10 = BI[(1 * 64 + lane) * 2 + 0];
    const floatx4 bi11 = BI[(1 * 64 + lane) * 2 + 1];
    const floatx4 bi20 = BI[(2 * 64 + lane) * 2 + 0];
    const floatx4 bi21 = BI[(2 * 64 + lane) * 2 + 1];
    const floatx4 bi30 = BI[(3 * 64 + lane) * 2 + 0];

    const half8 haf0 = __builtin_bit_cast(half8, af0);
    const half8 haf1 = __builtin_bit_cast(half8, af1);
    const half8 haf2 = __builtin_bit_cast(half8, af2);
    const half8 haf3 = __builtin_bit_cast(half8, af3);
    const half8 haf4 = __builtin_bit_cast(half8, af4);
    const half8 haf5 = __builtin_bit_cast(half8, af5);
    const half8 haf6 = __builtin_bit_cast(half8, af6);

    // ---- two pair-phases: groups {0,1} then {2,3}; 2-way ILP inside each ----
    #pragma unroll
    for (int ph = 0; ph < 2; ++ph) {
        // build B-frags for groups 2*ph (from dA) and 2*ph+1 (from dB)
        int e0, e1, e2, e3, f0, f1, f2, f3;
        if (ph == 0) {
            const bool sel = (p == 0);
            e0 = sel ? dA0 : 0; e1 = sel ? dA1 : 0; e2 = sel ? dA2 : 0; e3 = sel ? dA3 : 0;
            f0 = sel ? dB0 : 0; f1 = sel ? dB1 : 0; f2 = sel ? dB2 : 0; f3 = sel ? dB3 : 0;
        } else {
            const bool sel = (lane < 32);
            const int sA0 = __shfl_xor(dA0, 32), sA1 = __shfl_xor(dA1, 32);
            const int sA2 = __shfl_xor(dA2, 32), sA3 = __shfl_xor(dA3, 32);
            const int sB0 = __shfl_xor(dB0, 32), sB1 = __shfl_xor(dB1, 32);
            const int sB2 = __shfl_xor(dB2, 32), sB3 = __shfl_xor(dB3, 32);
            e0 = sel ? sA0 : 0; e1 = sel ? sA1 : 0; e2 = sel ? sA2 : 0; e3 = sel ? sA3 : 0;
            f0 = sel ? sB0 : 0; f1 = sel ? sB1 : 0; f2 = sel ? sB2 : 0; f3 = sel ? sB3 : 0;
        }
        half8 B0 = __builtin_bit_cast(half8, make_int4(e0, e1, e2, e3));
        half8 B1 = __builtin_bit_cast(half8, make_int4(f0, f1, f2, f3));

        // layer in
        floatx4 a00 = bi00, a01 = bi01, a10 = bi00, a11 = bi01;
        a00 = __builtin_amdgcn_mfma_f32_16x16x32_f16(haf0, B0, a00, 0, 0, 0);
        a10 = __builtin_amdgcn_mfma_f32_16x16x32_f16(haf0, B1, a10, 0, 0, 0);
        a01 = __builtin_amdgcn_mfma_f32_16x16x32_f16(haf1, B0, a01, 0, 0, 0);
        a11 = __builtin_amdgcn_mfma_f32_16x16x32_f16(haf1, B1, a11, 0, 0, 0);
        B0 = ln_b(0, a00, a01, lane, LP);
        B1 = ln_b(0, a10, a11, lane, LP);

        // hidden 0
        a00 = bi10; a01 = bi11; a10 = bi10; a11 = bi11;
        a00 = __builtin_amdgcn_mfma_f32_16x16x32_f16(haf2, B0, a00, 0, 0, 0);
        a10 = __builtin_amdgcn_mfma_f32_16x16x32_f16(haf2, B1, a10, 0, 0, 0);
        a01 = __builtin_amdgcn_mfma_f32_16x16x32_f16(haf3, B0, a01, 0, 0, 0);
        a11 = __builtin_amdgcn_mfma_f32_16x16x32_f16(haf3, B1, a11, 0, 0, 0);
        B0 = ln_b(1, a00, a01, lane, LP);
        B1 = ln_b(1, a10, a11, lane, LP);

        // hidden 1
        a00 = bi20; a01 = bi21; a10 = bi20; a11 = bi21;
        a00 = __builtin_amdgcn_mfma_f32_16x16x32_f16(haf4, B0, a00, 0, 0, 0);
        a10 = __builtin_amdgcn_mfma_f32_16x16x32_f16(haf4, B1, a10, 0, 0, 0);
        a01 = __builtin_amdgcn_mfma_f32_16x16x32_f16(haf5, B0, a01, 0, 0, 0);
        a11 = __builtin_amdgcn_mfma_f32_16x16x32_f16(haf5, B1, a11, 0, 0, 0);
        B0 = ln_b(2, a00, a01, lane, LP);
        B1 = ln_b(2, a10, a11, lane, LP);

        // out layer
        floatx4 o0 = bi30, o1 = bi30;
        o0 = __builtin_amdgcn_mfma_f32_16x16x32_f16(haf6, B0, o0, 0, 0, 0);
        o1 = __builtin_amdgcn_mfma_f32_16x16x32_f16(haf6, B1, o1, 0, 0, 0);

        if (lane < 16) {
            const size_t r0 = (size_t)(ray_base + (2 * ph) * 16 + lane) * 3;
            out[r0 + 0] = o0[0];
            out[r0 + 1] = o0[1];
            out[r0 + 2] = o0[2];
            const size_t r1 = (size_t)(ray_base + (2 * ph + 1) * 16 + lane) * 3;
            out[r1 + 0] = o1[0];
            out[r1 + 1] = o1[1];
            out[r1 + 2] = o1[2];
        }
    }
}

// ---------------- fallback: direct fp32 gather + scalar MLP ----------------
__device__ __forceinline__ void ln_relu_apply(float* __restrict__ pre,
                                              const float* __restrict__ g,
                                              const float* __restrict__ bt,
                                              float* __restrict__ h) {
    float m = 0.0f;
    #pragma unroll
    for (int j = 0; j < HID; ++j) m += pre[j];
    m *= (1.0f / HID);
    float v = 0.0f;
    #pragma unroll
    for (int j = 0; j < HID; ++j) { pre[j] -= m; v = fmaf(pre[j], pre[j], v); }
    const float r = rsqrtf(fmaf(v, (1.0f / HID), LN_EPS));
    #pragma unroll
    for (int j = 0; j < HID; ++j)
        h[j] = fmaxf(0.0f, fmaf(pre[j] * r, g[j], bt[j]));
}

__global__ __launch_bounds__(256, 4) void ray_mlp_direct(
    const float* __restrict__ inputs, const float* __restrict__ tex,
    const float* __restrict__ w_in,  const float* __restrict__ b_in,
    const float* __restrict__ g_in,  const float* __restrict__ bt_in,
    const float* __restrict__ w_hid, const float* __restrict__ b_hid,
    const float* __restrict__ g_hid, const float* __restrict__ bt_hid,
    const float* __restrict__ w_out, const float* __restrict__ b_out,
    float* __restrict__ out) {
    const int ray = blockIdx.x * 256 + threadIdx.x;
    const float4 in0 = *reinterpret_cast<const float4*>(inputs + (size_t)ray * 8);
    const float4 in1 = *reinterpret_cast<const float4*>(inputs + (size_t)ray * 8 + 4);
    const float th[NSPH] = {in0.x, in0.z, in1.x, in1.z};
    const float ph[NSPH] = {in0.y, in0.w, in1.y, in1.w};
    float x[DIN];
    #pragma unroll
    for (int s = 0; s < NSPH; ++s) {
        float fx = th[s] * CX, fy = ph[s] * CY;
        const bool fin = isfinite(fx) && isfinite(fy);
        const float fmv = fin ? 1.0f : 0.0f;
        fx = fin ? fx : 0.0f; fy = fin ? fy : 0.0f;
        const float fx0 = floorf(fx), fy0 = floorf(fy);
        const float xf = fx - fx0, yf = fy - fy0;
        const int x0 = min(max((int)fx0, 0), TEXW - 1);
        const int x1 = min(max((int)ceilf(fx), 0), TEXW - 1);
        const int y0 = min(max((int)fy0, 0), TEXH - 1);
        const int y1 = min(max((int)ceilf(fy), 0), TEXH - 1);
        const float4* img = reinterpret_cast<const float4*>(tex) + (size_t)s * TEXH * TEXW;
        const float4 t00 = img[(size_t)y0 * TEXW + x0];
        const float4 t01 = img[(size_t)y0 * TEXW + x1];
        const float4 t10 = img[(size_t)y1 * TEXW + x0];
        const float4 t11 = img[(size_t)y1 * TEXW + x1];
        float tp0 = fmaf(xf, t01.x - t00.x, t00.x), tp1 = fmaf(xf, t01.y - t00.y, t00.y);
        float tp2 = fmaf(xf, t01.z - t00.z, t00.z), tp3 = fmaf(xf, t01.w - t00.w, t00.w);
        float bt0 = fmaf(xf, t11.x - t10.x, t10.x), bt1 = fmaf(xf, t11.y - t10.y, t10.y);
        float bt2 = fmaf(xf, t11.z - t10.z, t10.z), bt3 = fmaf(xf, t11.w - t10.w, t10.w);
        x[4*s+0] = fmaf(yf, bt0 - tp0, tp0) * fmv;
        x[4*s+1] = fmaf(yf, bt1 - tp1, tp1) * fmv;
        x[4*s+2] = fmaf(yf, bt2 - tp2, tp2) * fmv;
        x[4*s+3] = fmaf(yf, bt3 - tp3, tp3) * fmv;
    }
    float pre[HID], h[HID];
    #pragma unroll
    for (int j = 0; j < HID; ++j) pre[j] = b_in[j];
    #pragma unroll
    for (int k = 0; k < DIN; ++k) {
        const float xv = x[k];
        #pragma unroll
        for (int j = 0; j < HID; ++j)
            pre[j] = fmaf(xv, w_in[k * HID + j], pre[j]);
    }
    ln_relu_apply(pre, g_in, bt_in, h);
    #pragma unroll
    for (int l = 0; l < 2; ++l) {
        const float* __restrict__ W  = w_hid  + l * HID * HID;
        const float* __restrict__ bb = b_hid  + l * HID;
        const float* __restrict__ gg = g_hid  + l * HID;
        const float* __restrict__ bt = bt_hid + l * HID;
        #pragma unroll
        for (int j = 0; j < HID; ++j) pre[j] = bb[j];
        #pragma unroll
        for (int k = 0; k < HID; ++k) {
            const float hv = h[k];
            #pragma unroll
            for (int j = 0; j < HID; ++j)
                pre[j] = fmaf(hv, W[k * HID + j], pre[j]);
        }
        ln_relu_apply(pre, gg, bt, h);
    }
    float o0 = b_out[0], o1 = b_out[1], o2 = b_out[2];
    #pragma unroll
    for (int k = 0; k < HID; ++k) {
        const float hv = h[k];
        o0 = fmaf(hv, w_out[k * NOUT + 0], o0);
        o1 = fmaf(hv, w_out[k * NOUT + 1], o1);
        o2 = fmaf(hv, w_out[k * NOUT + 2], o2);
    }
    out[(size_t)ray * NOUT + 0] = o0;
    out[(size_t)ray * NOUT + 1] = o1;
    out[(size_t)ray * NOUT + 2] = o2;
}

extern "C" void kernel_launch(void* const* d_in, const int* in_sizes, int n_in,
                              void* d_out, int out_size, void* d_ws, size_t ws_size,
                              hipStream_t stream) {
    const float* inputs = (const float*)d_in[0];
    const float* tex    = (const float*)d_in[1];
    const float* w_in   = (const float*)d_in[2];
    const float* b_in   = (const float*)d_in[3];
    const float* g_in   = (const float*)d_in[4];
    const float* bt_in  = (const float*)d_in[5];
    const float* w_hid  = (const float*)d_in[6];
    const float* b_hid  = (const float*)d_in[7];
    const float* g_hid  = (const float*)d_in[8];
    const float* bt_hid = (const float*)d_in[9];
    const float* w_out  = (const float*)d_in[10];
    const float* b_out  = (const float*)d_in[11];
    float* out = (float*)d_out;

    if (ws_size >= WS_NEEDED) {
        char* wsb = (char*)d_ws;
        uint4* Q = (uint4*)wsb;
        relayout_kernel<<<dim3(QW / 256, QROWS, NSPH), 256, 0, stream>>>(tex, Q);
        prep_w<<<1, 64, 0, stream>>>(w_in, b_in, g_in, bt_in,
                                     w_hid, b_hid, g_hid, bt_hid,
                                     w_out, b_out, wsb);
        ray_mlp_mfma<<<NRAYS / 256, 256, 0, stream>>>(inputs, Q, wsb, out);
    } else {
        ray_mlp_direct<<<NRAYS / 256, 256, 0, stream>>>(
            inputs, tex, w_in, b_in, g_in, bt_in,
            w_hid, b_hid, g_hid, bt_hid, w_out, b_out, out);
    }
}